// Round 10
// baseline (452.894 us; speedup 1.0000x reference)
//
#include <hip/hip_runtime.h>

typedef unsigned short ushort_t;

__device__ __forceinline__ float u2f(ushort_t u){
    union{unsigned int i; float f;} x; x.i = ((unsigned int)u) << 16; return x.f;
}
__device__ __forceinline__ ushort_t f2u(float f){   // f32 -> bf16 bits, RNE
    union{float fl; unsigned int i;} x; x.fl = f;
    unsigned int r = x.i + 0x7FFFu + ((x.i >> 16) & 1u);
    return (ushort_t)(r >> 16);
}

#define REP10(M) M(0)M(1)M(2)M(3)M(4)M(5)M(6)M(7)M(8)M(9)
#define REP16(M) M(0)M(1)M(2)M(3)M(4)M(5)M(6)M(7)M(8)M(9)M(10)M(11)M(12)M(13)M(14)M(15)
#define REP22(M) REP16(M) M(16)M(17)M(18)M(19)M(20)M(21)
#define REP55(M) M(0)M(1)M(2)M(3)M(4)M(5)M(6)M(7)M(8)M(9)M(10)M(11)M(12)M(13)M(14)M(15)M(16)M(17)M(18)M(19)M(20)M(21)M(22)M(23)M(24)M(25)M(26)M(27)M(28)M(29)M(30)M(31)M(32)M(33)M(34)M(35)M(36)M(37)M(38)M(39)M(40)M(41)M(42)M(43)M(44)M(45)M(46)M(47)M(48)M(49)M(50)M(51)M(52)M(53)M(54)

// ================= Kernel 1: h = x@cw+cb ; 4x { h += LN16(h@pw+pb) } -> ws bf16 ===
// Channel attention collapses (softmax rows sum to 1 -> einsum == identity on x).
// Weights in LDS read as float4 with immediate offsets (in-order DS returns
// pipeline; SMEM s_loads return out-of-order and force lgkmcnt(0) serialization).
// 2 rows/thread so each weight read feeds 32 FMAs. Named scalars only.
__global__ __launch_bounds__(256)
void k_embed(const float* __restrict__ X,
             const float* __restrict__ CW, const float* __restrict__ CB,
             const float* __restrict__ PW, const float* __restrict__ PB,
             const float* __restrict__ PG, const float* __restrict__ PBE,
             ushort_t* __restrict__ Hws)
{
    __shared__ __align__(16) float sW[672];       // CW@0 CB@352 PW@368 PB@624 PG@640 PBE@656
    __shared__ __align__(16) float sX[512*23];    // 512 staged rows, stride 23
    const int t = threadIdx.x;
    const int base = blockIdx.x * 512;            // grid 1000 -> rows exact

    for (int i = t; i < 352; i += 256) sW[i] = CW[i];
    for (int i = t; i < 256; i += 256) sW[368+i] = PW[i];
    if (t < 16){ sW[352+t]=CB[t]; sW[624+t]=PB[t]; sW[640+t]=PG[t]; sW[656+t]=PBE[t]; }
    {
        const float2* src = (const float2*)(X + (size_t)base*22);
        for (int i = t; i < 5632; i += 256){
            int r = i/11, c = (i - r*11)*2;
            float2 v = src[i];
            sX[r*23+c] = v.x; sX[r*23+c+1] = v.y;
        }
    }
    __syncthreads();

    const float* xa = sX + t*23;
    const float* xb = sX + (t+256)*23;

#define E_DV(c) float va##c, vb##c; { const float b0 = sW[352+(c)]; va##c=b0; vb##c=b0; }
    REP16(E_DV)
#define E_CH(j) { const float4 wA = *(const float4*)(sW+(j)*16); \
    const float4 wB = *(const float4*)(sW+(j)*16+4); \
    const float4 wC = *(const float4*)(sW+(j)*16+8); \
    const float4 wD = *(const float4*)(sW+(j)*16+12); \
    const float xA = xa[j], xB = xb[j]; \
    va0+=xA*wA.x; va1+=xA*wA.y; va2+=xA*wA.z; va3+=xA*wA.w; \
    va4+=xA*wB.x; va5+=xA*wB.y; va6+=xA*wB.z; va7+=xA*wB.w; \
    va8+=xA*wC.x; va9+=xA*wC.y; va10+=xA*wC.z; va11+=xA*wC.w; \
    va12+=xA*wD.x; va13+=xA*wD.y; va14+=xA*wD.z; va15+=xA*wD.w; \
    vb0+=xB*wA.x; vb1+=xB*wA.y; vb2+=xB*wA.z; vb3+=xB*wA.w; \
    vb4+=xB*wB.x; vb5+=xB*wB.y; vb6+=xB*wB.z; vb7+=xB*wB.w; \
    vb8+=xB*wC.x; vb9+=xB*wC.y; vb10+=xB*wC.z; vb11+=xB*wC.w; \
    vb12+=xB*wD.x; vb13+=xB*wD.y; vb14+=xB*wD.z; vb15+=xB*wD.w; }
    REP22(E_CH)

#define E_DU(c) float ua##c, ub##c; { const float b0 = sW[624+(c)]; ua##c=b0; ub##c=b0; }
#define E_PJ(j) { const float4 wA = *(const float4*)(sW+368+(j)*16); \
    const float4 wB = *(const float4*)(sW+368+(j)*16+4); \
    const float4 wC = *(const float4*)(sW+368+(j)*16+8); \
    const float4 wD = *(const float4*)(sW+368+(j)*16+12); \
    ua0+=va##j*wA.x; ua1+=va##j*wA.y; ua2+=va##j*wA.z; ua3+=va##j*wA.w; \
    ua4+=va##j*wB.x; ua5+=va##j*wB.y; ua6+=va##j*wB.z; ua7+=va##j*wB.w; \
    ua8+=va##j*wC.x; ua9+=va##j*wC.y; ua10+=va##j*wC.z; ua11+=va##j*wC.w; \
    ua12+=va##j*wD.x; ua13+=va##j*wD.y; ua14+=va##j*wD.z; ua15+=va##j*wD.w; \
    ub0+=vb##j*wA.x; ub1+=vb##j*wA.y; ub2+=vb##j*wA.z; ub3+=vb##j*wA.w; \
    ub4+=vb##j*wB.x; ub5+=vb##j*wB.y; ub6+=vb##j*wB.z; ub7+=vb##j*wB.w; \
    ub8+=vb##j*wC.x; ub9+=vb##j*wC.y; ub10+=vb##j*wC.z; ub11+=vb##j*wC.w; \
    ub12+=vb##j*wD.x; ub13+=vb##j*wD.y; ub14+=vb##j*wD.z; ub15+=vb##j*wD.w; }
#define E_DS(c) const float da##c = ua##c - ma; const float db##c = ub##c - mb;
#define E_UP(c) { const float g = sW[640+(c)], be = sW[656+(c)]; \
    va##c += da##c * inva * g + be; vb##c += db##c * invb * g + be; }
#define E_LNIT { \
    REP16(E_DU) REP16(E_PJ) \
    const float ma = ((((ua0+ua1)+(ua2+ua3))+((ua4+ua5)+(ua6+ua7)))+(((ua8+ua9)+(ua10+ua11))+((ua12+ua13)+(ua14+ua15))))*0.0625f; \
    const float mb = ((((ub0+ub1)+(ub2+ub3))+((ub4+ub5)+(ub6+ub7)))+(((ub8+ub9)+(ub10+ub11))+((ub12+ub13)+(ub14+ub15))))*0.0625f; \
    REP16(E_DS) \
    const float vara = ((((da0*da0+da1*da1)+(da2*da2+da3*da3))+((da4*da4+da5*da5)+(da6*da6+da7*da7)))+(((da8*da8+da9*da9)+(da10*da10+da11*da11))+((da12*da12+da13*da13)+(da14*da14+da15*da15))))*0.0625f; \
    const float varb = ((((db0*db0+db1*db1)+(db2*db2+db3*db3))+((db4*db4+db5*db5)+(db6*db6+db7*db7)))+(((db8*db8+db9*db9)+(db10*db10+db11*db11))+((db12*db12+db13*db13)+(db14*db14+db15*db15))))*0.0625f; \
    const float inva = rsqrtf(vara + 1e-5f); \
    const float invb = rsqrtf(varb + 1e-5f); \
    REP16(E_UP) }

    E_LNIT E_LNIT E_LNIT E_LNIT

    {
        const int row0 = base + t;
        const int b0 = row0 / 1000, s0 = row0 - b0*1000;
        ushort_t* hp = Hws + b0*16000 + s0;
#define E_STA(c) hp[(c)*1000] = f2u(va##c);
        REP16(E_STA)
    }
    {
        const int row1 = base + t + 256;
        const int b1 = row1 / 1000, s1 = row1 - b1*1000;
        ushort_t* hp = Hws + b1*16000 + s1;
#define E_STB(c) hp[(c)*1000] = f2u(vb##c);
        REP16(E_STB)
    }
}

// ================= Kernel 2: conv1+BN+LReLU fused into conv2 -> t (ws f32) ========
// (unchanged this round: isolates the s_load-weight cost in the counters)
__global__ __launch_bounds__(256)
void k_conv(const ushort_t* __restrict__ Hws,
            const float* __restrict__ W1, const float* __restrict__ B1,
            const float* __restrict__ BNG, const float* __restrict__ BNB,
            const float* __restrict__ BNM, const float* __restrict__ BNV,
            const float* __restrict__ W2, const float* __restrict__ B2,
            float* __restrict__ Tws)
{
    __shared__ ushort_t sH[16000];   // h[16][1000] bf16 = 32 KB
    const int tid = threadIdx.x, b = blockIdx.x;

    {
        const uint4* src = (const uint4*)(Hws + b*16000);
        uint4* dst = (uint4*)sH;
        for (int i = tid; i < 2000; i += 256) dst[i] = src[i];
    }
    const float sc0 = BNG[0]*rsqrtf(BNV[0]+1e-5f);
    const float sc1 = BNG[1]*rsqrtf(BNV[1]+1e-5f);
    const float sh0 = BNB[0] + (B1[0]-BNM[0])*sc0;
    const float sh1 = BNB[1] + (B1[1]-BNM[1])*sc1;
    __syncthreads();

    if (tid < 190){
        const int w5 = tid*5;
#define C_DT(o) float t##o = B2[o];
        REP10(C_DT)
        const float* w1a = W1;
        const float* w1b = W1 + 51;
        for (int kh = 0; kh < 16; ++kh){
            const ushort_t* hp = sH + kh*1000 + w5;
            float a0=0.f,a1=0.f,a2=0.f,a3=0.f,a4=0.f;
            float b0_=0.f,b1_=0.f,b2_=0.f,b3_=0.f,b4_=0.f;
#define C_TAP(e) { const float cur = u2f(hp[e]); \
            if ((e) < 51)              { a0+=cur*w1a[(e)];   b0_+=cur*w1b[(e)];   } \
            if ((e) >= 1 && (e) < 52)  { a1+=cur*w1a[(e)-1]; b1_+=cur*w1b[(e)-1]; } \
            if ((e) >= 2 && (e) < 53)  { a2+=cur*w1a[(e)-2]; b2_+=cur*w1b[(e)-2]; } \
            if ((e) >= 3 && (e) < 54)  { a3+=cur*w1a[(e)-3]; b3_+=cur*w1b[(e)-3]; } \
            if ((e) >= 4)              { a4+=cur*w1a[(e)-4]; b4_+=cur*w1b[(e)-4]; } }
            REP55(C_TAP)
#define C_LR(q) { a##q = a##q*sc0 + sh0; a##q = a##q > 0.f ? a##q : 0.2f*a##q; \
                  b##q##_ = b##q##_*sc1 + sh1; b##q##_ = b##q##_ > 0.f ? b##q##_ : 0.2f*b##q##_; }
            C_LR(0) C_LR(1) C_LR(2) C_LR(3) C_LR(4)
#define C_C2(o) { const float* wa = W2 + (((o)*2  )*16 + kh)*5; \
                  const float* wb = W2 + (((o)*2+1)*16 + kh)*5; \
        t##o += a0*wa[0]+a1*wa[1]+a2*wa[2]+a3*wa[3]+a4*wa[4] \
              + b0_*wb[0]+b1_*wb[1]+b2_*wb[2]+b3_*wb[3]+b4_*wb[4]; }
            REP10(C_C2)
        }
        float* op = Tws + (size_t)b*1900 + tid*10;
#define C_ST(o) op[o] = t##o;
        REP10(C_ST)
    }
}

// ================= Kernel 3: 3 transformer layers (n=190, e=10, 5 heads, d=2) =====
// All weights staged in LDS with b128-friendly padded layout (rows padded to 12):
// per-layer stride 1536 floats:
//   ln1g@0 ln1b@12 qw@24(10x12) qb@144 kw@156 kb@276 vw@288 vb@408
//   ow@420 ob@540 ln2g@552 ln2b@564 f1w@576(10x40) f1b@976 f2w@1016(40x12) f2b@1496
__global__ __launch_bounds__(256)
void k_tf(const float* __restrict__ Tws,
          const float* __restrict__ LN1G, const float* __restrict__ LN1B,
          const float* __restrict__ QW, const float* __restrict__ QBv,
          const float* __restrict__ KW, const float* __restrict__ KBv,
          const float* __restrict__ VW, const float* __restrict__ VBv,
          const float* __restrict__ OW, const float* __restrict__ OBv,
          const float* __restrict__ LN2G, const float* __restrict__ LN2B,
          const float* __restrict__ F1W, const float* __restrict__ F1B,
          const float* __restrict__ F2W, const float* __restrict__ F2B,
          float* __restrict__ OUT)
{
    __shared__ __align__(16) float TW[3*1536];
    __shared__ __align__(16) float T [190*11];
    __shared__ __align__(16) float QB[190*12];
    __shared__ __align__(16) float KB[190*12];
    __shared__ __align__(16) float VB[190*12];
    __shared__ __align__(16) float AT[190*12];

    const int tid = threadIdx.x, b = blockIdx.x;

    // ---- stage weights into padded LDS layout ----
    for (int i = tid; i < 30; i += 256){ int L=i/10, j=i-L*10;
        TW[L*1536 +    j] = LN1G[i];  TW[L*1536 + 12 + j] = LN1B[i];
        TW[L*1536 +144 + j] = QBv[i]; TW[L*1536 +276 + j] = KBv[i];
        TW[L*1536 +408 + j] = VBv[i]; TW[L*1536 +540 + j] = OBv[i];
        TW[L*1536 +552 + j] = LN2G[i];TW[L*1536 +564 + j] = LN2B[i];
        TW[L*1536+1496 + j] = F2B[i];
    }
    for (int i = tid; i < 300; i += 256){ int L=i/100, r=(i-L*100)/10, c=i%10;
        TW[L*1536 + 24 + r*12 + c] = QW[i];
        TW[L*1536 +156 + r*12 + c] = KW[i];
        TW[L*1536 +288 + r*12 + c] = VW[i];
        TW[L*1536 +420 + r*12 + c] = OW[i];
    }
    for (int i = tid; i < 1200; i += 256){ int L=i/400, r=i-L*400;
        TW[L*1536 + 576 + r] = F1W[i];               // [c][40], j-contiguous
        int rr = r/10, cc = r - rr*10;
        TW[L*1536 +1016 + rr*12 + cc] = F2W[i];      // rows j padded to 12
    }
    for (int i = tid; i < 120; i += 256){ int L=i/40, j=i-L*40;
        TW[L*1536 + 976 + j] = F1B[i];
    }
    for (int i = tid; i < 1900; i += 256){
        int r = i/10, c = i - r*10;
        T[r*11 + c] = Tws[(size_t)b*1900 + i];
    }
    __syncthreads();

    const float LSCALE = (float)(0.31622776601683794 * 1.4426950408889634); // 1/sqrt(10)*log2(e)
    const bool act = (tid < 190);
#pragma unroll 1
    for (int L = 0; L < 3; ++L){
        const float* Wb = TW + L*1536;

        // ---- phase 1: LN1 + Q/K/V projections (190 threads) ----
        if (act){
#define T_TV(c) float tv##c = T[tid*11 + c];
            REP10(T_TV)
            float m = ((((tv0+tv1)+(tv2+tv3))+((tv4+tv5)+(tv6+tv7)))+(tv8+tv9))*0.1f;
#define T_D1(c) const float e1##c = tv##c - m;
            REP10(T_D1)
            float var = ((((e10*e10+e11*e11)+(e12*e12+e13*e13))+((e14*e14+e15*e15)+(e16*e16+e17*e17)))+(e18*e18+e19*e19))*0.1f;
            float inv = rsqrtf(var + 1e-5f);
#define T_Y(c) const float y##c = e1##c*inv*Wb[c] + Wb[12+c];
            REP10(T_Y)
#define T_PJ(j, WO) { const float4 wA = *(const float4*)(Wb+(WO)+(j)*12); \
    const float4 wB_ = *(const float4*)(Wb+(WO)+(j)*12+4); \
    const float2 wC_ = *(const float2*)(Wb+(WO)+(j)*12+8); \
    a0+=y##j*wA.x; a1+=y##j*wA.y; a2+=y##j*wA.z; a3+=y##j*wA.w; \
    a4+=y##j*wB_.x; a5+=y##j*wB_.y; a6+=y##j*wB_.z; a7+=y##j*wB_.w; \
    a8+=y##j*wC_.x; a9+=y##j*wC_.y; }
#define T_PROJ(DST, WO, BO) { \
    float a0=Wb[(BO)+0],a1=Wb[(BO)+1],a2=Wb[(BO)+2],a3=Wb[(BO)+3],a4=Wb[(BO)+4]; \
    float a5=Wb[(BO)+5],a6=Wb[(BO)+6],a7=Wb[(BO)+7],a8=Wb[(BO)+8],a9=Wb[(BO)+9]; \
    T_PJ(0,WO) T_PJ(1,WO) T_PJ(2,WO) T_PJ(3,WO) T_PJ(4,WO) \
    T_PJ(5,WO) T_PJ(6,WO) T_PJ(7,WO) T_PJ(8,WO) T_PJ(9,WO) \
    float4 s1; s1.x=a0; s1.y=a1; s1.z=a2; s1.w=a3; \
    float4 s2; s2.x=a4; s2.y=a5; s2.z=a6; s2.w=a7; \
    float2 s3; s3.x=a8; s3.y=a9; \
    *(float4*)((DST)+tid*12) = s1; *(float4*)((DST)+tid*12+4) = s2; \
    *(float2*)((DST)+tid*12+8) = s3; }
            T_PROJ(QB, 24, 144)
            T_PROJ(KB, 156, 276)
            T_PROJ(VB, 288, 408)
        }
        __syncthreads();

        // ---- phase 2: attention, head-major (240 threads; 4 queries/thread) ----
        // no-max softmax: logits O(1); jax's max-shift is mathematically identity.
        if (tid < 240){
            const int h5 = tid / 48;
            const int qg = tid - h5*48;
            const int q0 = qg * 4;
#define T_LQ(i) float qx##i, qy##i; { const int qi = q0 + i; \
            if (qi < 190){ qx##i = QB[qi*12 + 2*h5]*LSCALE; qy##i = QB[qi*12 + 2*h5 + 1]*LSCALE; } \
            else { qx##i = 0.f; qy##i = 0.f; } }
            T_LQ(0) T_LQ(1) T_LQ(2) T_LQ(3)
            float l0=0.f,l1=0.f,l2=0.f,l3=0.f;
            float p00=0.f,p01=0.f,p10=0.f,p11=0.f,p20=0.f,p21=0.f,p30=0.f,p31=0.f;
            const float* kp = KB + 2*h5;
            const float* vp = VB + 2*h5;
#pragma unroll 2
            for (int kk = 0; kk < 190; ++kk){
                const float2 kv = *(const float2*)(kp + kk*12);
                const float2 vv = *(const float2*)(vp + kk*12);
                const float e0 = exp2f(qx0*kv.x + qy0*kv.y);
                const float e1 = exp2f(qx1*kv.x + qy1*kv.y);
                const float e2 = exp2f(qx2*kv.x + qy2*kv.y);
                const float e3 = exp2f(qx3*kv.x + qy3*kv.y);
                l0 += e0; p00 += e0*vv.x; p01 += e0*vv.y;
                l1 += e1; p10 += e1*vv.x; p11 += e1*vv.y;
                l2 += e2; p20 += e2*vv.x; p21 += e2*vv.y;
                l3 += e3; p30 += e3*vv.x; p31 += e3*vv.y;
            }
#define T_SA(i) { const int qi = q0 + i; if (qi < 190){ const float rl = 1.f/l##i; \
                  AT[qi*12 + 2*h5] = p##i##0*rl; AT[qi*12 + 2*h5 + 1] = p##i##1*rl; } }
            T_SA(0) T_SA(1) T_SA(2) T_SA(3)
        }
        __syncthreads();

        // ---- phase 3: out-proj + residual + LN2 + FF(GELU exact) + residual ----
        if (act){
#define T_TV2(c) float w##c = T[tid*11 + c];
            REP10(T_TV2)
            const float4 atA = *(const float4*)(AT + tid*12);
            const float4 atB = *(const float4*)(AT + tid*12 + 4);
            const float2 atC = *(const float2*)(AT + tid*12 + 8);
            const float at0=atA.x, at1=atA.y, at2=atA.z, at3=atA.w;
            const float at4=atB.x, at5=atB.y, at6=atB.z, at7=atB.w;
            const float at8=atC.x, at9=atC.y;
            {
                float a0=Wb[540+0],a1=Wb[540+1],a2=Wb[540+2],a3=Wb[540+3],a4=Wb[540+4];
                float a5=Wb[540+5],a6=Wb[540+6],a7=Wb[540+7],a8=Wb[540+8],a9=Wb[540+9];
#define T_PO(j) { const float4 wA = *(const float4*)(Wb+420+(j)*12); \
    const float4 wB_ = *(const float4*)(Wb+420+(j)*12+4); \
    const float2 wC_ = *(const float2*)(Wb+420+(j)*12+8); \
    a0+=at##j*wA.x; a1+=at##j*wA.y; a2+=at##j*wA.z; a3+=at##j*wA.w; \
    a4+=at##j*wB_.x; a5+=at##j*wB_.y; a6+=at##j*wB_.z; a7+=at##j*wB_.w; \
    a8+=at##j*wC_.x; a9+=at##j*wC_.y; }
                T_PO(0) T_PO(1) T_PO(2) T_PO(3) T_PO(4)
                T_PO(5) T_PO(6) T_PO(7) T_PO(8) T_PO(9)
                w0+=a0; w1+=a1; w2+=a2; w3+=a3; w4+=a4;
                w5+=a5; w6+=a6; w7+=a7; w8+=a8; w9+=a9;
            }
            float m2 = ((((w0+w1)+(w2+w3))+((w4+w5)+(w6+w7)))+(w8+w9))*0.1f;
#define T_D2(c) const float e2##c = w##c - m2;
            REP10(T_D2)
            float var2 = ((((e20*e20+e21*e21)+(e22*e22+e23*e23))+((e24*e24+e25*e25)+(e26*e26+e27*e27)))+(e28*e28+e29*e29))*0.1f;
            float inv2 = rsqrtf(var2 + 1e-5f);
#define T_Z(c) const float z##c = e2##c*inv2*Wb[552+c] + Wb[564+c];
            REP10(T_Z)
#define T_DD(c) float dd##c = Wb[1496+c];
            REP10(T_DD)
#pragma unroll 1
            for (int jb = 0; jb < 10; ++jb){
                const float* f1p = Wb + 576 + jb*4;
                const float4 b4 = *(const float4*)(Wb + 976 + jb*4);
                float A0=b4.x, A1=b4.y, A2=b4.z, A3=b4.w;
#define T_FF1(c) { const float4 wc = *(const float4*)(f1p + (c)*40); \
                A0+=z##c*wc.x; A1+=z##c*wc.y; A2+=z##c*wc.z; A3+=z##c*wc.w; }
                REP10(T_FF1)
#define T_G(q) const float g##q = 0.5f*A##q*(1.f + erff(A##q*0.70710678118654752f));
                T_G(0) T_G(1) T_G(2) T_G(3)
                const float* f2p = Wb + 1016 + jb*48;
#define T_FF2(q) { const float4 wA = *(const float4*)(f2p + (q)*12); \
    const float4 wB_ = *(const float4*)(f2p + (q)*12 + 4); \
    const float2 wC_ = *(const float2*)(f2p + (q)*12 + 8); \
    dd0+=g##q*wA.x; dd1+=g##q*wA.y; dd2+=g##q*wA.z; dd3+=g##q*wA.w; \
    dd4+=g##q*wB_.x; dd5+=g##q*wB_.y; dd6+=g##q*wB_.z; dd7+=g##q*wB_.w; \
    dd8+=g##q*wC_.x; dd9+=g##q*wC_.y; }
                T_FF2(0) T_FF2(1) T_FF2(2) T_FF2(3)
            }
#define T_WB(c) T[tid*11 + c] = w##c + dd##c;
            REP10(T_WB)
        }
        __syncthreads();
    }

    if (act){
        float* op = OUT + (size_t)b*1900 + tid*10;
#define T_OUT(c) op[c] = T[tid*11 + c];
        REP10(T_OUT)
    }
}

extern "C" void kernel_launch(void* const* d_in, const int* in_sizes, int n_in,
                              void* d_out, int out_size, void* d_ws, size_t ws_size,
                              hipStream_t stream)
{
    (void)ws_size; (void)n_in; (void)out_size;
    const int B = in_sizes[0] / 22000;   // 512
    auto in = [&](int i){ return (const float*)d_in[i]; };
    ushort_t* Hws = (ushort_t*)d_ws;                              // B*16000 bf16 = 16.38 MB
    float*    Tws = (float*)((char*)d_ws + (size_t)B*16000*2);    // B*1900 f32

    k_embed<<<(B*1000)/512, 256, 0, stream>>>(
        in(0), in(1), in(2), in(11), in(12), in(13), in(14), Hws);

    k_conv<<<B, 256, 0, stream>>>(
        Hws, in(15), in(16), in(17), in(18), in(19), in(20), in(21), in(22), Tws);

    k_tf<<<B, 256, 0, stream>>>(
        Tws,
        in(23), in(24), in(25), in(26), in(27), in(28), in(29), in(30),
        in(31), in(32), in(33), in(34), in(35), in(36), in(37), in(38),
        (float*)d_out);
}